// Round 1
// baseline (606.165 us; speedup 1.0000x reference)
//
#include <hip/hip_runtime.h>

typedef __bf16 bf16;
typedef __attribute__((ext_vector_type(8))) __bf16 bf16x8;
typedef __attribute__((ext_vector_type(4))) float f32x4;
typedef __attribute__((ext_vector_type(4))) unsigned short u16x4;
typedef __attribute__((ext_vector_type(8))) unsigned short u16x8;
typedef __attribute__((ext_vector_type(4))) float float4v;

#define MFMA16(a,b,c) __builtin_amdgcn_mfma_f32_16x16x32_bf16((a),(b),(c),0,0,0)

// Problem dims: B=8, C=768, H=W=64, S=H*W=4096, CK=96, L=CK*H=6144, D=W=64
// Workspace layout (bytes):
static constexpr size_t OFF_WQKV = 0;                                   // [288][768] bf16 (Wq,Wk,Wv stacked)
static constexpr size_t OFF_WC   = OFF_WQKV + (size_t)288*768*2;        // [768][96] bf16
static constexpr size_t OFF_QKV  = OFF_WC   + (size_t)768*96*2;         // [8][288][4096] bf16
static constexpr size_t OFF_A    = OFF_QKV  + (size_t)8*288*4096*2;     // [8][96][4096] bf16
static constexpr size_t OFF_AT   = OFF_A    + (size_t)8*96*4096*2;      // [8][4096][96] bf16
// total ~32.1 MB

// ---------------- k0: convert weights to bf16 ----------------
__global__ __launch_bounds__(256) void k_wcvt(const float* __restrict__ Wq,
                                              const float* __restrict__ Wk,
                                              const float* __restrict__ Wv,
                                              const float* __restrict__ Wc,
                                              bf16* __restrict__ Wqkv,
                                              bf16* __restrict__ Wcb) {
  int t = blockIdx.x * 256 + threadIdx.x;   // 73728 float4 groups total
  int base = t * 4;
  float4v v;
  if (base < 73728)        v = ((const float4v*)Wq)[t];
  else if (base < 147456)  v = ((const float4v*)Wk)[t - 18432];
  else if (base < 221184)  v = ((const float4v*)Wv)[t - 36864];
  else                     v = ((const float4v*)Wc)[t - 55296];
  u16x4 o;
  #pragma unroll
  for (int i = 0; i < 4; ++i) {
    bf16 h = (bf16)v[i];
    o[i] = __builtin_bit_cast(unsigned short, h);
  }
  if (base < 221184) ((u16x4*)Wqkv)[t] = o;
  else               ((u16x4*)Wcb)[t - 55296] = o;
}

// ---------------- k1: fused QKV projection  QKV[b][o3][s] = Wqkv[o3][:] . x[b][:][s]
// block: 6 waves (384 thr), tile M=288 (all q,k,v rows), N=64 spatial.
// x chunk [96 c][64 s] staged transposed+swizzled into LDS as bf16.
__global__ __launch_bounds__(384) void k_proj(const float* __restrict__ x,
                                              const bf16* __restrict__ Wqkv,
                                              bf16* __restrict__ QKV) {
  __shared__ __align__(16) unsigned char ldsT[64 * 256];   // T'[s][c padded to 128] bf16, swz ^((s&7)<<4)
  const int t = threadIdx.x, wid = t >> 6, l = t & 63;
  const int b = blockIdx.y, s0 = blockIdx.x * 64;
  const int lq = l >> 4, lr = l & 15;
  f32x4 acc[3][4] = {};
  for (int ch = 0; ch < 8; ++ch) {
    const int cbase = ch * 96;
    // stage: thread handles s=l, c-chunks of 8
    #pragma unroll
    for (int it = 0; it < 2; ++it) {
      int c0 = wid * 8 + it * 48;
      bf16x8 pk;
      #pragma unroll
      for (int j = 0; j < 8; ++j)
        pk[j] = (bf16)x[(size_t)(b * 768 + cbase + c0 + j) * 4096 + s0 + l];
      *(bf16x8*)(ldsT + ((l * 256 + c0 * 2) ^ ((l & 7) << 4))) = pk;
    }
    __syncthreads();
    #pragma unroll
    for (int kk = 0; kk < 3; ++kk) {
      bf16x8 af[3], bv[4];
      #pragma unroll
      for (int ma = 0; ma < 3; ++ma) {
        int row = wid * 48 + ma * 16 + lr;
        af[ma] = *(const bf16x8*)&Wqkv[(size_t)row * 768 + cbase + kk * 32 + lq * 8];
      }
      #pragma unroll
      for (int nb = 0; nb < 4; ++nb) {
        int sl = nb * 16 + lr;
        bv[nb] = *(const bf16x8*)(ldsT + ((sl * 256 + (kk * 32 + lq * 8) * 2) ^ ((sl & 7) << 4)));
      }
      #pragma unroll
      for (int ma = 0; ma < 3; ++ma)
        #pragma unroll
        for (int nb = 0; nb < 4; ++nb)
          acc[ma][nb] = MFMA16(af[ma], bv[nb], acc[ma][nb]);
    }
    __syncthreads();
  }
  #pragma unroll
  for (int ma = 0; ma < 3; ++ma)
    #pragma unroll
    for (int nb = 0; nb < 4; ++nb)
      #pragma unroll
      for (int i = 0; i < 4; ++i) {
        int o3 = wid * 48 + ma * 16 + lq * 4 + i;
        int s  = s0 + nb * 16 + lr;
        QKV[((size_t)b * 288 + o3) * 4096 + s] = (bf16)acc[ma][nb][i];
      }
}

// ---------------- k2: flash attention over [6144,64], 96 KV tiles of 64
// block = (qb,b): 64 q-rows, 4 waves x 16 rows. Swapped QK^T so lane owns one q-row.
__global__ __launch_bounds__(256) void k_attn(const bf16* __restrict__ QKV,
                                              bf16* __restrict__ A) {
  __shared__ __align__(16) unsigned char Pl[4][2048];   // per-wave P[16][64] bf16, swz ^((row&7)<<4)
  __shared__ __align__(16) unsigned char Vt[8192];      // Vt[w][64 kv] bf16,  swz ^((w&7)<<4)
  const int t = threadIdx.x, wid = t >> 6, l = t & 63;
  const int b = blockIdx.y, qb = blockIdx.x;
  const int lq = l >> 4, lr = l & 15;
  const bf16* Qb = QKV + (size_t)b * 288 * 4096;
  const bf16* Kb = Qb + (size_t)96 * 4096;
  const bf16* Vb = Qb + (size_t)192 * 4096;
  const int qr = qb * 64 + wid * 16 + lr;
  bf16x8 qf[2];
  qf[0] = *(const bf16x8*)&Qb[(size_t)qr * 64 + lq * 8];
  qf[1] = *(const bf16x8*)&Qb[(size_t)qr * 64 + 32 + lq * 8];
  f32x4 oacc[4] = {};
  float m2 = -INFINITY, lsum = 0.f;
  const float LOG2E = 1.44269504f;
  unsigned char* Pw = Pl[wid];
  for (int kt = 0; kt < 96; ++kt) {
    // S^T = K_tile @ Q^T   (lane -> q-row lr, kcols kb*16 + lq*4 + i)
    f32x4 st[4] = {};
    #pragma unroll
    for (int kb = 0; kb < 4; ++kb) {
      #pragma unroll
      for (int kk = 0; kk < 2; ++kk) {
        bf16x8 kf = *(const bf16x8*)&Kb[(size_t)(kt * 64 + kb * 16 + lr) * 64 + kk * 32 + lq * 8];
        st[kb] = MFMA16(kf, qf[kk], st[kb]);
      }
    }
    // stage V tile transposed: Vt[w][kv]
    {
      const bf16* vr = &Vb[(size_t)(kt * 64 + l) * 64 + wid * 16];
      u16x8 v0 = *(const u16x8*)vr;
      u16x8 v1 = *(const u16x8*)(vr + 8);
      #pragma unroll
      for (int e = 0; e < 8; ++e) {
        int w = wid * 16 + e;
        *(unsigned short*)(Vt + ((w * 128 + l * 2) ^ ((w & 7) << 4))) = v0[e];
      }
      #pragma unroll
      for (int e = 0; e < 8; ++e) {
        int w = wid * 16 + 8 + e;
        *(unsigned short*)(Vt + ((w * 128 + l * 2) ^ ((w & 7) << 4))) = v1[e];
      }
    }
    // online softmax in base-2
    float tm = st[0][0];
    #pragma unroll
    for (int kb = 0; kb < 4; ++kb)
      #pragma unroll
      for (int i = 0; i < 4; ++i) tm = fmaxf(tm, st[kb][i]);
    tm = fmaxf(tm, __shfl_xor(tm, 16));
    tm = fmaxf(tm, __shfl_xor(tm, 32));
    float m2n = fmaxf(m2, tm * LOG2E);
    float alpha = exp2f(m2 - m2n);            // first tile: exp2(-inf)=0
    float p[16], rs = 0.f;
    #pragma unroll
    for (int kb = 0; kb < 4; ++kb)
      #pragma unroll
      for (int i = 0; i < 4; ++i) {
        float pv = exp2f(fmaf(st[kb][i], LOG2E, -m2n));
        p[kb * 4 + i] = pv; rs += pv;
      }
    rs += __shfl_xor(rs, 16);
    rs += __shfl_xor(rs, 32);
    lsum = lsum * alpha + rs;
    m2 = m2n;
    float al[4];
    #pragma unroll
    for (int i = 0; i < 4; ++i) al[i] = __shfl(alpha, lq * 4 + i);
    #pragma unroll
    for (int wb = 0; wb < 4; ++wb)
      #pragma unroll
      for (int i = 0; i < 4; ++i) oacc[wb][i] *= al[i];
    // write P (bf16) to per-wave LDS: P[row=lr][kcol]
    #pragma unroll
    for (int kb = 0; kb < 4; ++kb)
      #pragma unroll
      for (int pr = 0; pr < 2; ++pr) {
        int kcol = kb * 16 + lq * 4 + pr * 2;
        bf16 b0 = (bf16)p[kb * 4 + pr * 2], b1 = (bf16)p[kb * 4 + pr * 2 + 1];
        unsigned int u = (unsigned int)__builtin_bit_cast(unsigned short, b0)
                       | ((unsigned int)__builtin_bit_cast(unsigned short, b1) << 16);
        *(unsigned int*)(Pw + ((lr * 128 + kcol * 2) ^ ((lr & 7) << 4))) = u;
      }
    __syncthreads();
    // O += P @ V
    #pragma unroll
    for (int kk = 0; kk < 2; ++kk) {
      bf16x8 pa = *(const bf16x8*)(Pw + ((lr * 128 + kk * 64 + lq * 16) ^ ((lr & 7) << 4)));
      #pragma unroll
      for (int wb = 0; wb < 4; ++wb) {
        int w = wb * 16 + lr;
        bf16x8 vf = *(const bf16x8*)(Vt + ((w * 128 + kk * 64 + lq * 16) ^ ((w & 7) << 4)));
        oacc[wb] = MFMA16(pa, vf, oacc[wb]);
      }
    }
    __syncthreads();
  }
  float linv[4];
  #pragma unroll
  for (int i = 0; i < 4; ++i) {
    float li = __shfl(lsum, lq * 4 + i);
    linv[i] = 1.0f / li;
  }
  bf16* Ab = A + (size_t)b * 96 * 4096;
  #pragma unroll
  for (int wb = 0; wb < 4; ++wb)
    #pragma unroll
    for (int i = 0; i < 4; ++i) {
      int row = qb * 64 + wid * 16 + lq * 4 + i;
      Ab[(size_t)row * 64 + wb * 16 + lr] = (bf16)(oacc[wb][i] * linv[i]);
    }
}

// ---------------- k2b: transpose A[b][96][4096] -> At[b][4096][96] (bf16)
__global__ __launch_bounds__(256) void k_at(const bf16* __restrict__ A,
                                            bf16* __restrict__ At) {
  __shared__ unsigned char T[96 * 128];   // T[c][s] bf16, stride 128B, dword-granule double-XOR swz
  const int t = threadIdx.x;
  const int b = blockIdx.y, s0 = blockIdx.x * 64;
  #pragma unroll
  for (int it = 0; it < 6; ++it) {
    int c = (t >> 4) + it * 16;
    int s = (t & 15) * 4;
    u16x4 va = *(const u16x4*)&A[((size_t)b * 96 + c) * 4096 + s0 + s];
    #pragma unroll
    for (int pr = 0; pr < 2; ++pr) {
      unsigned int u = (unsigned int)va[pr * 2] | ((unsigned int)va[pr * 2 + 1] << 16);
      int byte = (c * 128 + (s + pr * 2) * 2) ^ ((c & 7) << 2) ^ (((c >> 3) & 3) << 5);
      *(unsigned int*)(T + byte) = u;
    }
  }
  __syncthreads();
  int s = t >> 2, c0 = (t & 3) * 24;
  unsigned short us[24];
  #pragma unroll
  for (int e = 0; e < 24; ++e) {
    int c = c0 + e;
    int byte = (c * 128 + s * 2) ^ ((c & 7) << 2) ^ (((c >> 3) & 3) << 5);
    us[e] = *(const unsigned short*)(T + byte);
  }
  bf16* dst = At + ((size_t)b * 4096 + s0 + s) * 96 + c0;
  #pragma unroll
  for (int v8 = 0; v8 < 3; ++v8) {
    u16x8 o;
    #pragma unroll
    for (int e = 0; e < 8; ++e) o[e] = us[v8 * 8 + e];
    *(u16x8*)(dst + v8 * 8) = o;
  }
}

// ---------------- k3: out = gamma * (Wc @ A) + x  (fp32 out)
// block: 4 waves, tile M=256 (of 768), N=64; K=96. All operands direct-from-global.
__global__ __launch_bounds__(256) void k_out(const float* __restrict__ x,
                                             const bf16* __restrict__ Wcb,
                                             const bf16* __restrict__ At,
                                             const float* __restrict__ gamma,
                                             float* __restrict__ out) {
  const int t = threadIdx.x, wid = t >> 6, l = t & 63;
  const int lq = l >> 4, lr = l & 15;
  const int b = blockIdx.z, mb = blockIdx.y, s0 = blockIdx.x * 64;
  f32x4 acc[4][4] = {};
  #pragma unroll
  for (int kk = 0; kk < 3; ++kk) {
    bf16x8 af[4], bv[4];
    #pragma unroll
    for (int ma = 0; ma < 4; ++ma) {
      int row = mb * 256 + wid * 64 + ma * 16 + lr;
      af[ma] = *(const bf16x8*)&Wcb[(size_t)row * 96 + kk * 32 + lq * 8];
    }
    #pragma unroll
    for (int nb = 0; nb < 4; ++nb) {
      int s = s0 + nb * 16 + lr;
      bv[nb] = *(const bf16x8*)&At[((size_t)b * 4096 + s) * 96 + kk * 32 + lq * 8];
    }
    #pragma unroll
    for (int ma = 0; ma < 4; ++ma)
      #pragma unroll
      for (int nb = 0; nb < 4; ++nb)
        acc[ma][nb] = MFMA16(af[ma], bv[nb], acc[ma][nb]);
  }
  float g = gamma[0];
  #pragma unroll
  for (int ma = 0; ma < 4; ++ma)
    #pragma unroll
    for (int nb = 0; nb < 4; ++nb)
      #pragma unroll
      for (int i = 0; i < 4; ++i) {
        int o2 = mb * 256 + wid * 64 + ma * 16 + lq * 4 + i;
        int s  = s0 + nb * 16 + lr;
        size_t idx = ((size_t)b * 768 + o2) * 4096 + s;
        out[idx] = fmaf(acc[ma][nb][i], g, x[idx]);
      }
}

extern "C" void kernel_launch(void* const* d_in, const int* in_sizes, int n_in,
                              void* d_out, int out_size, void* d_ws, size_t ws_size,
                              hipStream_t stream) {
  (void)in_sizes; (void)n_in; (void)out_size; (void)ws_size;
  const float* x     = (const float*)d_in[0];
  const float* Wq    = (const float*)d_in[1];
  const float* Wk    = (const float*)d_in[2];
  const float* Wv    = (const float*)d_in[3];
  const float* Wc    = (const float*)d_in[4];
  const float* gamma = (const float*)d_in[5];
  float* out = (float*)d_out;
  char* ws = (char*)d_ws;
  bf16* Wqkv = (bf16*)(ws + OFF_WQKV);
  bf16* Wcb  = (bf16*)(ws + OFF_WC);
  bf16* QKV  = (bf16*)(ws + OFF_QKV);
  bf16* A    = (bf16*)(ws + OFF_A);
  bf16* At   = (bf16*)(ws + OFF_AT);

  k_wcvt<<<dim3(288), dim3(256), 0, stream>>>(Wq, Wk, Wv, Wc, Wqkv, Wcb);
  k_proj<<<dim3(64, 8), dim3(384), 0, stream>>>(x, Wqkv, QKV);
  k_attn<<<dim3(96, 8), dim3(256), 0, stream>>>(QKV, A);
  k_at<<<dim3(64, 8), dim3(256), 0, stream>>>(A, At);
  k_out<<<dim3(64, 3, 8), dim3(256), 0, stream>>>(x, Wcb, At, gamma, out);
}